// Round 1
// baseline (678.350 us; speedup 1.0000x reference)
//
#include <hip/hip_runtime.h>

#define D_MODEL 512
#define NUM_NEURONS 1024

// One 64-lane wave computes one output row: out[row] = dot(x[row,:], W[row%N,:]) + b[row%N]
// D=512 f32 = 128 float4; lane i reads float4 #i and #(i+64) -> two coalesced 1KiB wave loads.
__global__ __launch_bounds__(256) void neuron_dot_kernel(
    const float* __restrict__ x,   // [B*N, D]
    const float* __restrict__ W,   // [N, D]
    const float* __restrict__ b,   // [N]
    float* __restrict__ out,       // [B*N]
    int nrows) {

    const int lane   = threadIdx.x & 63;
    const int gwave  = (int)((blockIdx.x * blockDim.x + threadIdx.x) >> 6);
    const int nwaves = (int)((gridDim.x * blockDim.x) >> 6);

    for (int row = gwave; row < nrows; row += nwaves) {
        const int n = row & (NUM_NEURONS - 1);
        const float4* xr = reinterpret_cast<const float4*>(x + (size_t)row * D_MODEL);
        const float4* wr = reinterpret_cast<const float4*>(W + (size_t)n * D_MODEL);

        float4 xa = xr[lane];
        float4 wa = wr[lane];
        float4 xb = xr[lane + 64];
        float4 wb = wr[lane + 64];

        float s = xa.x * wa.x + xa.y * wa.y + xa.z * wa.z + xa.w * wa.w
                + xb.x * wb.x + xb.y * wb.y + xb.z * wb.z + xb.w * wb.w;

        // 64-lane wave reduction
        #pragma unroll
        for (int off = 32; off > 0; off >>= 1)
            s += __shfl_down(s, off, 64);

        if (lane == 0)
            out[row] = s + b[n];
    }
}

extern "C" void kernel_launch(void* const* d_in, const int* in_sizes, int n_in,
                              void* d_out, int out_size, void* d_ws, size_t ws_size,
                              hipStream_t stream) {
    const float* x = (const float*)d_in[0];
    const float* W = (const float*)d_in[1];
    const float* b = (const float*)d_in[2];
    float* out = (float*)d_out;

    const int nrows = out_size;  // B * N = 262144

    const int block = 256;
    const int grid  = 2048;  // 8192 waves, grid-stride over 262144 rows

    neuron_dot_kernel<<<grid, block, 0, stream>>>(x, W, b, out, nrows);
}